// Round 4
// baseline (163.323 us; speedup 1.0000x reference)
//
#include <hip/hip_runtime.h>
#include <hip/hip_fp16.h>

#define H0 200
#define W0 304
#define H1 100
#define W1 152
#define H2 50
#define W2 76
#define CPL 256   // channels per level
#define CTOT 768
#define OH 7
#define OW 7
#define NPOS 49
#define CBLK 128   // channels per stage-2 block
#define SROWP 131  // sout row stride (floats): 128 + 3 pad (131%32=3, coprime)

#define P0 (H0*W0)   // 60800
#define P1 (H1*W1)   // 15200
#define P2 (H2*W2)   // 3800
#define T0_OFF ((size_t)0)
#define T1_OFF ((size_t)P0*CPL)
#define T2_OFF ((size_t)P0*CPL + (size_t)P1*CPL)
#define WS_ELEMS ((size_t)P0*CPL + (size_t)P1*CPL + (size_t)P2*CPL)
#define WS_BYTES (WS_ELEMS * 2)   // fp16 workspace: 40,857,600 B

__device__ __forceinline__ float hat01(float d) {
    return fmaxf(0.0f, 1.0f - fabsf(d));
}

__device__ __forceinline__ unsigned short f2h_rne(float x) {
    return __half_as_ushort(__float2half_rn(x));
}

// ------------- Stage 1: fused [C][P] fp32 -> [P][C] fp16 transpose ----------
__global__ void __launch_bounds__(256)
transpose_all_kernel(const float* __restrict__ f0, const float* __restrict__ f1,
                     const float* __restrict__ f2,
                     unsigned short* __restrict__ T0,
                     unsigned short* __restrict__ T1,
                     unsigned short* __restrict__ T2, int n0, int n01) {
    __shared__ unsigned short tile[64][72];   // [p_local][c_local]
    int b = blockIdx.x;
    const float* in; unsigned short* outp; int P; int rel;
    if (b < n0)       { in = f0; outp = T0; P = P0; rel = b; }
    else if (b < n01) { in = f1; outp = T1; P = P1; rel = b - n0; }
    else              { in = f2; outp = T2; P = P2; rel = b - n01; }
    int p0 = (rel >> 2) * 64;
    int c0 = (rel & 3) * 64;

    int q = threadIdx.x & 15;     // p-quad
    int r = threadIdx.x >> 4;     // 0..15 (c)
    bool full = (p0 + 64 <= P);
#pragma unroll
    for (int i = 0; i < 4; ++i) {
        int c = c0 + r + 16 * i;
        int p = p0 + 4 * q;
        float4 v;
        if (full) {
            v = *(const float4*)(in + (size_t)c * P + p);
        } else {
            v.x = (p + 0 < P) ? in[(size_t)c * P + p + 0] : 0.0f;
            v.y = (p + 1 < P) ? in[(size_t)c * P + p + 1] : 0.0f;
            v.z = (p + 2 < P) ? in[(size_t)c * P + p + 2] : 0.0f;
            v.w = (p + 3 < P) ? in[(size_t)c * P + p + 3] : 0.0f;
        }
        tile[4 * q + 0][r + 16 * i] = f2h_rne(v.x);
        tile[4 * q + 1][r + 16 * i] = f2h_rne(v.y);
        tile[4 * q + 2][r + 16 * i] = f2h_rne(v.z);
        tile[4 * q + 3][r + 16 * i] = f2h_rne(v.w);
    }
    __syncthreads();
    int q8 = threadIdx.x & 7;     // c-octet
    int r8 = threadIdx.x >> 3;    // 0..31 (p)
#pragma unroll
    for (int i = 0; i < 2; ++i) {
        int p = p0 + r8 + 32 * i;
        if (p < P) {
            uint4 w = *(const uint4*)&tile[r8 + 32 * i][8 * q8];
            *(uint4*)(outp + (size_t)p * CPL + c0 + 8 * q8) = w;
        }
    }
}

// ------------- Stage 2: channels-last RoIAlign, 128-ch slab per block -------
// Block = (n, j), j in [0,6): level = j>>1, channel half = j&1. Each block
// computes ALL 49 positions for its 128 channels -> contiguous output slab.
// R4: combine R2's occupancy (6 blocks/CU, 24 waves) with R3's gather ILP by
// chunking the in-flight load array on BOTH axes: v[CHY][CHX] (24-32 VGPR)
// + per-row half2 partials q[CHY][4] persisting across x-chunks (accumulation
// order bitwise-identical to R3). ~75 VGPR -> fits launch_bounds(256,6);
// LDS 26.6KB x 6 = 159.7KB/CU (exact fit). 24 waves/CU x 6-8 loads in
// flight each hides the ~300cy L2 gather latency; co-resident blocks
// backfill the 49th-position wave imbalance.
template<int TY, int TX, int CHY, int CHX>
__device__ __forceinline__ void tap_loop(const char* __restrict__ Tb,
                                         const int (*__restrict__ s_idx)[6],
                                         const float (*__restrict__ s_w)[6],
                                         float (*__restrict__ sout)[SROWP],
                                         int grp, int col, unsigned laneByte) {
    const __half2 hz = __float2half2_rn(0.0f);
    for (int pos = grp; pos < NPOS; pos += 16) {
        int oh = pos / 7;
        int ow = pos - oh * 7;
        unsigned yb[TY]; float yw[TY];
#pragma unroll
        for (int j = 0; j < TY; ++j) {
            yb[j] = (unsigned)s_idx[oh][j] + laneByte;
            yw[j] = s_w[oh][j];
        }
        unsigned xb[TX]; __half2 xw2[TX];
#pragma unroll
        for (int j = 0; j < TX; ++j) {
            xb[j] = (unsigned)s_idx[7 + ow][j];
            xw2[j] = __float2half2_rn(s_w[7 + ow][j]);
        }
        float a0 = 0.f, a1 = 0.f, a2 = 0.f, a3 = 0.f;
        float a4 = 0.f, a5 = 0.f, a6 = 0.f, a7 = 0.f;
#pragma unroll
        for (int r0 = 0; r0 < TY; r0 += CHY) {
            __half2 q[CHY][4];
#pragma unroll
            for (int r = 0; r < CHY; ++r) {
                q[r][0] = hz; q[r][1] = hz; q[r][2] = hz; q[r][3] = hz;
            }
#pragma unroll
            for (int b0 = 0; b0 < TX; b0 += CHX) {
                uint4 v[CHY][CHX];
                // phase A: issue this chunk's loads (independent, SADDR)
#pragma unroll
                for (int r = 0; r < CHY; ++r) {
                    if (r0 + r < TY) {
#pragma unroll
                        for (int b = 0; b < CHX; ++b)
                            if (b0 + b < TX)
                                v[r][b] = *(const uint4*)(Tb + (yb[r0 + r] + xb[b0 + b]));
                    }
                }
                // phase B: consume into per-row half2 partials
#pragma unroll
                for (int r = 0; r < CHY; ++r) {
                    if (r0 + r < TY) {
#pragma unroll
                        for (int b = 0; b < CHX; ++b) {
                            if (b0 + b < TX) {
                                __half2 xw = xw2[b0 + b];
                                q[r][0] = __hfma2(xw, *(const __half2*)&v[r][b].x, q[r][0]);
                                q[r][1] = __hfma2(xw, *(const __half2*)&v[r][b].y, q[r][1]);
                                q[r][2] = __hfma2(xw, *(const __half2*)&v[r][b].z, q[r][2]);
                                q[r][3] = __hfma2(xw, *(const __half2*)&v[r][b].w, q[r][3]);
                            }
                        }
                    }
                }
            }
            // fold rows into fp32 accumulators
#pragma unroll
            for (int r = 0; r < CHY; ++r) {
                if (r0 + r < TY) {
                    float wa = yw[r0 + r];
                    a0 = fmaf(wa, __low2float(q[r][0]), a0);  a1 = fmaf(wa, __high2float(q[r][0]), a1);
                    a2 = fmaf(wa, __low2float(q[r][1]), a2);  a3 = fmaf(wa, __high2float(q[r][1]), a3);
                    a4 = fmaf(wa, __low2float(q[r][2]), a4);  a5 = fmaf(wa, __high2float(q[r][2]), a5);
                    a6 = fmaf(wa, __low2float(q[r][3]), a6);  a7 = fmaf(wa, __high2float(q[r][3]), a7);
                }
            }
        }
        float4 o0, o1;
        o0.x = a0 * 0.25f; o0.y = a1 * 0.25f; o0.z = a2 * 0.25f; o0.w = a3 * 0.25f;
        o1.x = a4 * 0.25f; o1.y = a5 * 0.25f; o1.z = a6 * 0.25f; o1.w = a7 * 0.25f;
        *(float4*)(&sout[pos][col])     = o0;
        *(float4*)(&sout[pos][col + 4]) = o1;
    }
}

__global__ void __launch_bounds__(256, 6)
roi_align_cl6_kernel(const unsigned short* __restrict__ T0p,
                     const unsigned short* __restrict__ T1p,
                     const unsigned short* __restrict__ T2p,
                     const float* __restrict__ boxes,
                     const int* __restrict__ img_h_p,
                     const int* __restrict__ img_w_p,
                     float* __restrict__ out) {
    __shared__ float sout[NPOS][SROWP];    // [pos][c_local]
    __shared__ int   s_idx[14][6];         // BYTE offsets: [0..6]=y(oh), [7..13]=x(ow)
    __shared__ float s_w[14][6];

    const int n = blockIdx.x;
    const int j = blockIdx.y;              // 0..5
    const int lev = j >> 1;
    const int chalf = j & 1;
    const int tid = threadIdx.x;

    const unsigned short* T; int Hc, Wc; float inv_s;
    if (lev == 0)      { T = T0p; Hc = H0; Wc = W0; inv_s = 1.0f;  }
    else if (lev == 1) { T = T1p; Hc = H1; Wc = W1; inv_s = 0.5f;  }
    else               { T = T2p; Hc = H2; Wc = W2; inv_s = 0.25f; }

    if (tid < 14) {
        int axis = (tid >= 7) ? 1 : 0;     // 0 = y, 1 = x
        int o = tid - axis * 7;
        float sx = (float)W0 / (float)img_w_p[0];
        float sy = (float)H0 / (float)img_h_p[0];
        float a1v, bs; int Hf, Hca, mul;
        if (axis) {
            a1v = boxes[n * 4 + 0] * sx;
            float a2v = boxes[n * 4 + 2] * sx;
            bs = fmaxf(a2v - a1v, 1.0f) * (1.0f / (float)OW);
            Hf = W0; Hca = Wc; mul = 1;
        } else {
            a1v = boxes[n * 4 + 1] * sy;
            float a2v = boxes[n * 4 + 3] * sy;
            bs = fmaxf(a2v - a1v, 1.0f) * (1.0f / (float)OH);
            Hf = H0; Hca = Hc; mul = Wc;
        }
        int idx[6]; float w[6];
#pragma unroll
        for (int t = 0; t < 6; ++t) { idx[t] = 0; w[t] = 0.0f; }
        if (lev == 0) {
#pragma unroll
            for (int r2 = 0; r2 < 2; ++r2) {
                float Y = a1v + ((float)o + 0.25f + 0.5f * (float)r2) * bs;
                float v = (Y >= -1.0f && Y <= (float)Hf) ? 1.0f : 0.0f;
                float Yc = fminf(fmaxf(Y, 0.0f), (float)(Hf - 1));
                int y0 = (int)Yc; float lf = Yc - (float)y0;
                idx[2 * r2]     = y0;                  w[2 * r2]     = (1.0f - lf) * v;
                idx[2 * r2 + 1] = min(y0 + 1, Hf - 1); w[2 * r2 + 1] = lf * v;
            }
        } else {
            int bases[2]; float w3[2][3];
#pragma unroll
            for (int r2 = 0; r2 < 2; ++r2) {
                float Y = a1v + ((float)o + 0.25f + 0.5f * (float)r2) * bs;
                float v = (Y >= -1.0f && Y <= (float)Hf) ? 1.0f : 0.0f;
                float Yc = fminf(fmaxf(Y, 0.0f), (float)(Hf - 1));
                int y0 = (int)Yc; float lf = Yc - (float)y0; float hf = 1.0f - lf;
                int yf1 = min(y0 + 1, Hf - 1);
                float yc0 = fminf(fmaxf(((float)y0 + 0.5f) * inv_s - 0.5f, 0.0f), (float)(Hca - 1));
                float yc1 = fminf(fmaxf(((float)yf1 + 0.5f) * inv_s - 0.5f, 0.0f), (float)(Hca - 1));
                int b2 = (int)yc0;
                bases[r2] = b2;
#pragma unroll
                for (int t2 = 0; t2 < 3; ++t2) {
                    float j2 = (float)(b2 + t2);
                    w3[r2][t2] = v * (hf * hat01(yc0 - j2) + lf * hat01(yc1 - j2));
                }
            }
            int dmax = (lev == 1) ? 3 : 2;   // geometry: box<=272px -> gap<=2.43/1.21
            int d = min(max(bases[1] - bases[0], 0), dmax);
            w[0] += w3[0][0]; w[1] += w3[0][1]; w[2] += w3[0][2];
            w[d] += w3[1][0]; w[d + 1] += w3[1][1]; w[d + 2] += w3[1][2];
#pragma unroll
            for (int t = 0; t < 6; ++t) idx[t] = min(bases[0] + t, Hca - 1);
        }
        // pre-scale to BYTE offset in T (row stride Wc*CPL elems, 2B/elem)
#pragma unroll
        for (int t = 0; t < 6; ++t) { s_idx[tid][t] = idx[t] * mul * CPL * 2; s_w[tid][t] = w[t]; }
    }
    __syncthreads();

    const int grp = tid >> 4;              // 0..15: position group
    const int l16 = tid & 15;              // 0..15: 8 channels each
    const int col = l16 * 8;               // local channel within the 128-slab
    const unsigned laneByte = (unsigned)(chalf * CBLK + col) * 2u;
    const char* Tb = (const char*)T;       // uniform base -> SADDR loads

    if (lev == 0)      tap_loop<4, 4, 2, 4>(Tb, s_idx, s_w, sout, grp, col, laneByte);
    else if (lev == 1) tap_loop<6, 6, 2, 3>(Tb, s_idx, s_w, sout, grp, col, laneByte);
    else               tap_loop<5, 5, 2, 3>(Tb, s_idx, s_w, sout, grp, col, laneByte);
    __syncthreads();

    // Writeback: out[n][lev*256 + chalf*128 + c][p], contiguous 128*49 floats.
    size_t obase = (size_t)n * CTOT * NPOS + (size_t)(lev * CPL + chalf * CBLK) * NPOS;
    int c = tid / NPOS;
    int p = tid - c * NPOS;
    for (int i = tid; i < CBLK * NPOS; i += 256) {
        out[obase + i] = sout[p][c];
        c += 5; p += 11;                   // 256 = 5*49 + 11
        if (p >= NPOS) { p -= NPOS; ++c; }
    }
}

// ---------------- Fallback (R1 kernel) if ws too small ----------------------
__device__ __forceinline__ void axis_w3_fb(int yf0, int Hf, int Hc, float inv_s,
                                           float lf, int& base, float* w) {
    int yf1 = min(yf0 + 1, Hf - 1);
    float hf = 1.0f - lf;
    float yc0 = fminf(fmaxf(((float)yf0 + 0.5f) * inv_s - 0.5f, 0.0f), (float)(Hc - 1));
    float yc1 = fminf(fmaxf(((float)yf1 + 0.5f) * inv_s - 0.5f, 0.0f), (float)(Hc - 1));
    base = (int)yc0;
#pragma unroll
    for (int r = 0; r < 3; ++r) {
        float j = (float)(base + r);
        w[r] = hf * hat01(yc0 - j) + lf * hat01(yc1 - j);
    }
}

__global__ void __launch_bounds__(256)
roi_align_fused_fb_kernel(const float* __restrict__ f0,
                          const float* __restrict__ f1,
                          const float* __restrict__ f2,
                          const float* __restrict__ boxes,
                          const int* __restrict__ img_h_p,
                          const int* __restrict__ img_w_p,
                          float* __restrict__ out,
                          int total) {
    int i = blockIdx.x * blockDim.x + threadIdx.x;
    if (i >= total) return;
    int ow = i % OW;
    int t = i / OW;
    int oh = t % OH; t /= OH;
    int c = t % CTOT;
    int n = t / CTOT;
    float sx = (float)W0 / (float)img_w_p[0];
    float sy = (float)H0 / (float)img_h_p[0];
    float bx1 = boxes[n * 4 + 0] * sx;
    float by1 = boxes[n * 4 + 1] * sy;
    float bw = fmaxf(boxes[n * 4 + 2] * sx - bx1, 1.0f) / OW;
    float bh = fmaxf(boxes[n * 4 + 3] * sy - by1, 1.0f) / OH;
    int level = c >> 8;
    int cl = c & (CPL - 1);
    const float* f;
    int Hc, Wc; float inv_s;
    if (level == 0)      { f = f0 + (size_t)cl * P0; Hc = H0; Wc = W0; inv_s = 1.0f;  }
    else if (level == 1) { f = f1 + (size_t)cl * P1; Hc = H1; Wc = W1; inv_s = 0.5f;  }
    else                 { f = f2 + (size_t)cl * P2; Hc = H2; Wc = W2; inv_s = 0.25f; }
    float acc = 0.0f;
#pragma unroll
    for (int ry = 0; ry < 2; ++ry) {
        float Y = by1 + ((float)oh + 0.25f + 0.5f * ry) * bh;
        bool vy = (Y >= -1.0f) && (Y <= (float)H0);
        float Yc = fminf(fmaxf(Y, 0.0f), (float)(H0 - 1));
        int y0 = (int)Yc;
        float ly = Yc - (float)y0;
#pragma unroll
        for (int rx = 0; rx < 2; ++rx) {
            float X = bx1 + ((float)ow + 0.25f + 0.5f * rx) * bw;
            bool vx = (X >= -1.0f) && (X <= (float)W0);
            float Xc = fminf(fmaxf(X, 0.0f), (float)(W0 - 1));
            int x0 = (int)Xc;
            float lx = Xc - (float)x0;
            float v;
            if (level == 0) {
                int y1i = min(y0 + 1, H0 - 1), x1i = min(x0 + 1, W0 - 1);
                float hy = 1.0f - ly, hx = 1.0f - lx;
                float v00 = f[y0 * W0 + x0],  v01 = f[y0 * W0 + x1i];
                float v10 = f[y1i * W0 + x0], v11 = f[y1i * W0 + x1i];
                v = hy * (hx * v00 + lx * v01) + ly * (hx * v10 + lx * v11);
            } else {
                int yb, xb; float wy[3], wxl[3];
                axis_w3_fb(y0, H0, Hc, inv_s, ly, yb, wy);
                axis_w3_fb(x0, W0, Wc, inv_s, lx, xb, wxl);
                v = 0.0f;
#pragma unroll
                for (int a = 0; a < 3; ++a) {
                    int row = min(yb + a, Hc - 1) * Wc;
                    float s = 0.0f;
#pragma unroll
                    for (int b = 0; b < 3; ++b)
                        s += wxl[b] * f[row + min(xb + b, Wc - 1)];
                    v += wy[a] * s;
                }
            }
            if (vy && vx) acc += v;
        }
    }
    out[i] = acc * 0.25f;
}

// ---------------- launch ----------------------------------------------------
extern "C" void kernel_launch(void* const* d_in, const int* in_sizes, int n_in,
                              void* d_out, int out_size, void* d_ws, size_t ws_size,
                              hipStream_t stream) {
    const float* f0    = (const float*)d_in[0];
    const float* f1    = (const float*)d_in[1];
    const float* f2    = (const float*)d_in[2];
    const float* boxes = (const float*)d_in[3];
    const int* img_h_p = (const int*)d_in[4];
    const int* img_w_p = (const int*)d_in[5];
    float* out = (float*)d_out;
    int N = in_sizes[3] / 4;

    if (ws_size >= WS_BYTES) {
        unsigned short* ws = (unsigned short*)d_ws;
        unsigned short* T0 = ws + T0_OFF;
        unsigned short* T1 = ws + T1_OFF;
        unsigned short* T2 = ws + T2_OFF;
        int n0 = ((P0 + 63) / 64) * 4;   // 3800
        int n1 = ((P1 + 63) / 64) * 4;   // 952
        int n2 = ((P2 + 63) / 64) * 4;   // 240
        transpose_all_kernel<<<n0 + n1 + n2, 256, 0, stream>>>(
            f0, f1, f2, T0, T1, T2, n0, n0 + n1);
        roi_align_cl6_kernel<<<dim3(N, 6), 256, 0, stream>>>(
            T0, T1, T2, boxes, img_h_p, img_w_p, out);
    } else {
        int total = N * CTOT * OH * OW;
        roi_align_fused_fb_kernel<<<(total + 255) / 256, 256, 0, stream>>>(
            f0, f1, f2, boxes, img_h_p, img_w_p, out, total);
    }
}

// Round 5
// 159.763 us; speedup vs baseline: 1.0223x; 1.0223x over previous
//
#include <hip/hip_runtime.h>
#include <hip/hip_fp16.h>

#define H0 200
#define W0 304
#define H1 100
#define W1 152
#define H2 50
#define W2 76
#define CPL 256   // channels per level
#define CTOT 768
#define OH 7
#define OW 7
#define NPOS 49
#define CBLK 128   // channels per stage-2 block
#define SROWP 131  // sout row stride (floats): 128 + 3 pad (131%32=3, coprime)

#define P0 (H0*W0)   // 60800
#define P1 (H1*W1)   // 15200
#define P2 (H2*W2)   // 3800
#define T0_OFF ((size_t)0)
#define T1_OFF ((size_t)P0*CPL)
#define T2_OFF ((size_t)P0*CPL + (size_t)P1*CPL)
#define WS_ELEMS ((size_t)P0*CPL + (size_t)P1*CPL + (size_t)P2*CPL)
#define WS_BYTES (WS_ELEMS * 2)   // fp16 workspace: 40,857,600 B

__device__ __forceinline__ float hat01(float d) {
    return fmaxf(0.0f, 1.0f - fabsf(d));
}

__device__ __forceinline__ unsigned short f2h_rne(float x) {
    return __half_as_ushort(__float2half_rn(x));
}

// ------------- Stage 1: fused [C][P] fp32 -> [P][C] fp16 transpose ----------
__global__ void __launch_bounds__(256)
transpose_all_kernel(const float* __restrict__ f0, const float* __restrict__ f1,
                     const float* __restrict__ f2,
                     unsigned short* __restrict__ T0,
                     unsigned short* __restrict__ T1,
                     unsigned short* __restrict__ T2, int n0, int n01) {
    __shared__ unsigned short tile[64][72];   // [p_local][c_local]
    int b = blockIdx.x;
    const float* in; unsigned short* outp; int P; int rel;
    if (b < n0)       { in = f0; outp = T0; P = P0; rel = b; }
    else if (b < n01) { in = f1; outp = T1; P = P1; rel = b - n0; }
    else              { in = f2; outp = T2; P = P2; rel = b - n01; }
    int p0 = (rel >> 2) * 64;
    int c0 = (rel & 3) * 64;

    int q = threadIdx.x & 15;     // p-quad
    int r = threadIdx.x >> 4;     // 0..15 (c)
    bool full = (p0 + 64 <= P);
#pragma unroll
    for (int i = 0; i < 4; ++i) {
        int c = c0 + r + 16 * i;
        int p = p0 + 4 * q;
        float4 v;
        if (full) {
            v = *(const float4*)(in + (size_t)c * P + p);
        } else {
            v.x = (p + 0 < P) ? in[(size_t)c * P + p + 0] : 0.0f;
            v.y = (p + 1 < P) ? in[(size_t)c * P + p + 1] : 0.0f;
            v.z = (p + 2 < P) ? in[(size_t)c * P + p + 2] : 0.0f;
            v.w = (p + 3 < P) ? in[(size_t)c * P + p + 3] : 0.0f;
        }
        tile[4 * q + 0][r + 16 * i] = f2h_rne(v.x);
        tile[4 * q + 1][r + 16 * i] = f2h_rne(v.y);
        tile[4 * q + 2][r + 16 * i] = f2h_rne(v.z);
        tile[4 * q + 3][r + 16 * i] = f2h_rne(v.w);
    }
    __syncthreads();
    int q8 = threadIdx.x & 7;     // c-octet
    int r8 = threadIdx.x >> 3;    // 0..31 (p)
#pragma unroll
    for (int i = 0; i < 2; ++i) {
        int p = p0 + r8 + 32 * i;
        if (p < P) {
            uint4 w = *(const uint4*)&tile[r8 + 32 * i][8 * q8];
            *(uint4*)(outp + (size_t)p * CPL + c0 + 8 * q8) = w;
        }
    }
}

// ------------- Stage 2: channels-last RoIAlign, 128-ch slab per block -------
// Block = (n, j), j in [0,6): level = j>>1, channel half = j&1. Each block
// computes ALL 49 positions for its 128 channels -> contiguous output slab.
// R5: the R2-R4 plateau was the compiler re-serializing gathers (VGPR=40
// proves the in-flight arrays collapsed; ~7 wave-loads in flight per CU vs
// ~400cy gather latency). Pin a 2-row software pipeline with
// sched_barrier(0): issue row r+1's TX loads -> sched_barrier -> consume
// row r. v[2][TX] double-buffer indexed only by unrolled compile-time r&1.
// launch_bounds(256,5) (VGPR cap 102) holds the ~90-reg budget; 5 blocks/CU.
// 16-lane groups own CONSECUTIVE position runs (3-4 each) for temporal L1
// strip reuse (small/medium boxes share tap strips between adjacent pos).
template<int TY, int TX>
__device__ __forceinline__ void tap_loop(const char* __restrict__ Tb,
                                         const int (*__restrict__ s_idx)[6],
                                         const float (*__restrict__ s_w)[6],
                                         float (*__restrict__ sout)[SROWP],
                                         int pstart, int pcount, int col,
                                         unsigned laneByte) {
    const __half2 hz = __float2half2_rn(0.0f);
    for (int pi = 0; pi < pcount; ++pi) {
        const int pos = pstart + pi;
        const int oh = pos / 7;
        const int ow = pos - oh * 7;
        unsigned yb[TY]; float yw[TY];
#pragma unroll
        for (int j2 = 0; j2 < TY; ++j2) {
            yb[j2] = (unsigned)s_idx[oh][j2] + laneByte;
            yw[j2] = s_w[oh][j2];
        }
        unsigned xb[TX]; __half2 xw2[TX];
#pragma unroll
        for (int j2 = 0; j2 < TX; ++j2) {
            xb[j2] = (unsigned)s_idx[7 + ow][j2];
            xw2[j2] = __float2half2_rn(s_w[7 + ow][j2]);
        }
        float a0 = 0.f, a1 = 0.f, a2 = 0.f, a3 = 0.f;
        float a4 = 0.f, a5 = 0.f, a6 = 0.f, a7 = 0.f;
        uint4 v[2][TX];
        // prologue: issue row 0's loads; barrier pins them before any use
#pragma unroll
        for (int b = 0; b < TX; ++b)
            v[0][b] = *(const uint4*)(Tb + (yb[0] + xb[b]));
        __builtin_amdgcn_sched_barrier(0);
#pragma unroll
        for (int r = 0; r < TY; ++r) {
            if (r + 1 < TY) {
                // issue next row BEFORE consuming current: compiler must emit
                // counted vmcnt (TX outstanding) instead of vmcnt(0)
#pragma unroll
                for (int b = 0; b < TX; ++b)
                    v[(r + 1) & 1][b] = *(const uint4*)(Tb + (yb[r + 1] + xb[b]));
                __builtin_amdgcn_sched_barrier(0);
            }
            __half2 q0 = hz, q1 = hz, q2 = hz, q3 = hz;
#pragma unroll
            for (int b = 0; b < TX; ++b) {
                const __half2 xw = xw2[b];
                q0 = __hfma2(xw, *(const __half2*)&v[r & 1][b].x, q0);
                q1 = __hfma2(xw, *(const __half2*)&v[r & 1][b].y, q1);
                q2 = __hfma2(xw, *(const __half2*)&v[r & 1][b].z, q2);
                q3 = __hfma2(xw, *(const __half2*)&v[r & 1][b].w, q3);
            }
            const float wa = yw[r];
            a0 = fmaf(wa, __low2float(q0), a0);  a1 = fmaf(wa, __high2float(q0), a1);
            a2 = fmaf(wa, __low2float(q1), a2);  a3 = fmaf(wa, __high2float(q1), a3);
            a4 = fmaf(wa, __low2float(q2), a4);  a5 = fmaf(wa, __high2float(q2), a5);
            a6 = fmaf(wa, __low2float(q3), a6);  a7 = fmaf(wa, __high2float(q3), a7);
        }
        float4 o0, o1;
        o0.x = a0 * 0.25f; o0.y = a1 * 0.25f; o0.z = a2 * 0.25f; o0.w = a3 * 0.25f;
        o1.x = a4 * 0.25f; o1.y = a5 * 0.25f; o1.z = a6 * 0.25f; o1.w = a7 * 0.25f;
        *(float4*)(&sout[pos][col])     = o0;
        *(float4*)(&sout[pos][col + 4]) = o1;
    }
}

__global__ void __launch_bounds__(256, 5)
roi_align_cl6_kernel(const unsigned short* __restrict__ T0p,
                     const unsigned short* __restrict__ T1p,
                     const unsigned short* __restrict__ T2p,
                     const float* __restrict__ boxes,
                     const int* __restrict__ img_h_p,
                     const int* __restrict__ img_w_p,
                     float* __restrict__ out) {
    __shared__ float sout[NPOS][SROWP];    // [pos][c_local]
    __shared__ int   s_idx[14][6];         // BYTE offsets: [0..6]=y(oh), [7..13]=x(ow)
    __shared__ float s_w[14][6];

    const int n = blockIdx.x;
    const int j = blockIdx.y;              // 0..5
    const int lev = j >> 1;
    const int chalf = j & 1;
    const int tid = threadIdx.x;

    const unsigned short* T; int Hc, Wc; float inv_s;
    if (lev == 0)      { T = T0p; Hc = H0; Wc = W0; inv_s = 1.0f;  }
    else if (lev == 1) { T = T1p; Hc = H1; Wc = W1; inv_s = 0.5f;  }
    else               { T = T2p; Hc = H2; Wc = W2; inv_s = 0.25f; }

    if (tid < 14) {
        int axis = (tid >= 7) ? 1 : 0;     // 0 = y, 1 = x
        int o = tid - axis * 7;
        float sx = (float)W0 / (float)img_w_p[0];
        float sy = (float)H0 / (float)img_h_p[0];
        float a1v, bs; int Hf, Hca, mul;
        if (axis) {
            a1v = boxes[n * 4 + 0] * sx;
            float a2v = boxes[n * 4 + 2] * sx;
            bs = fmaxf(a2v - a1v, 1.0f) * (1.0f / (float)OW);
            Hf = W0; Hca = Wc; mul = 1;
        } else {
            a1v = boxes[n * 4 + 1] * sy;
            float a2v = boxes[n * 4 + 3] * sy;
            bs = fmaxf(a2v - a1v, 1.0f) * (1.0f / (float)OH);
            Hf = H0; Hca = Hc; mul = Wc;
        }
        int idx[6]; float w[6];
#pragma unroll
        for (int t = 0; t < 6; ++t) { idx[t] = 0; w[t] = 0.0f; }
        if (lev == 0) {
#pragma unroll
            for (int r2 = 0; r2 < 2; ++r2) {
                float Y = a1v + ((float)o + 0.25f + 0.5f * (float)r2) * bs;
                float v = (Y >= -1.0f && Y <= (float)Hf) ? 1.0f : 0.0f;
                float Yc = fminf(fmaxf(Y, 0.0f), (float)(Hf - 1));
                int y0 = (int)Yc; float lf = Yc - (float)y0;
                idx[2 * r2]     = y0;                  w[2 * r2]     = (1.0f - lf) * v;
                idx[2 * r2 + 1] = min(y0 + 1, Hf - 1); w[2 * r2 + 1] = lf * v;
            }
        } else {
            int bases[2]; float w3[2][3];
#pragma unroll
            for (int r2 = 0; r2 < 2; ++r2) {
                float Y = a1v + ((float)o + 0.25f + 0.5f * (float)r2) * bs;
                float v = (Y >= -1.0f && Y <= (float)Hf) ? 1.0f : 0.0f;
                float Yc = fminf(fmaxf(Y, 0.0f), (float)(Hf - 1));
                int y0 = (int)Yc; float lf = Yc - (float)y0; float hf = 1.0f - lf;
                int yf1 = min(y0 + 1, Hf - 1);
                float yc0 = fminf(fmaxf(((float)y0 + 0.5f) * inv_s - 0.5f, 0.0f), (float)(Hca - 1));
                float yc1 = fminf(fmaxf(((float)yf1 + 0.5f) * inv_s - 0.5f, 0.0f), (float)(Hca - 1));
                int b2 = (int)yc0;
                bases[r2] = b2;
#pragma unroll
                for (int t2 = 0; t2 < 3; ++t2) {
                    float j2 = (float)(b2 + t2);
                    w3[r2][t2] = v * (hf * hat01(yc0 - j2) + lf * hat01(yc1 - j2));
                }
            }
            int dmax = (lev == 1) ? 3 : 2;   // geometry: box<=272px -> gap<=2.43/1.21
            int d = min(max(bases[1] - bases[0], 0), dmax);
            w[0] += w3[0][0]; w[1] += w3[0][1]; w[2] += w3[0][2];
            w[d] += w3[1][0]; w[d + 1] += w3[1][1]; w[d + 2] += w3[1][2];
#pragma unroll
            for (int t = 0; t < 6; ++t) idx[t] = min(bases[0] + t, Hca - 1);
        }
        // pre-scale to BYTE offset in T (row stride Wc*CPL elems, 2B/elem)
#pragma unroll
        for (int t = 0; t < 6; ++t) { s_idx[tid][t] = idx[t] * mul * CPL * 2; s_w[tid][t] = w[t]; }
    }
    __syncthreads();

    const int grp = tid >> 4;              // 0..15: position group
    const int l16 = tid & 15;              // 0..15: 8 channels each
    const int col = l16 * 8;               // local channel within the 128-slab
    const unsigned laneByte = (unsigned)(chalf * CBLK + col) * 2u;
    const char* Tb = (const char*)T;       // uniform base -> SADDR loads

    // consecutive-position runs: group g owns positions [3g, 3g+3) (g=15: +4)
    const int pstart = 3 * grp;
    const int pcount = (grp == 15) ? 4 : 3;

    if (lev == 0)      tap_loop<4, 4>(Tb, s_idx, s_w, sout, pstart, pcount, col, laneByte);
    else if (lev == 1) tap_loop<6, 6>(Tb, s_idx, s_w, sout, pstart, pcount, col, laneByte);
    else               tap_loop<5, 5>(Tb, s_idx, s_w, sout, pstart, pcount, col, laneByte);
    __syncthreads();

    // Writeback: out[n][lev*256 + chalf*128 + c][p], contiguous 128*49 floats.
    size_t obase = (size_t)n * CTOT * NPOS + (size_t)(lev * CPL + chalf * CBLK) * NPOS;
    int c = tid / NPOS;
    int p = tid - c * NPOS;
    for (int i = tid; i < CBLK * NPOS; i += 256) {
        out[obase + i] = sout[p][c];
        c += 5; p += 11;                   // 256 = 5*49 + 11
        if (p >= NPOS) { p -= NPOS; ++c; }
    }
}

// ---------------- Fallback (R1 kernel) if ws too small ----------------------
__device__ __forceinline__ void axis_w3_fb(int yf0, int Hf, int Hc, float inv_s,
                                           float lf, int& base, float* w) {
    int yf1 = min(yf0 + 1, Hf - 1);
    float hf = 1.0f - lf;
    float yc0 = fminf(fmaxf(((float)yf0 + 0.5f) * inv_s - 0.5f, 0.0f), (float)(Hc - 1));
    float yc1 = fminf(fmaxf(((float)yf1 + 0.5f) * inv_s - 0.5f, 0.0f), (float)(Hc - 1));
    base = (int)yc0;
#pragma unroll
    for (int r = 0; r < 3; ++r) {
        float j = (float)(base + r);
        w[r] = hf * hat01(yc0 - j) + lf * hat01(yc1 - j);
    }
}

__global__ void __launch_bounds__(256)
roi_align_fused_fb_kernel(const float* __restrict__ f0,
                          const float* __restrict__ f1,
                          const float* __restrict__ f2,
                          const float* __restrict__ boxes,
                          const int* __restrict__ img_h_p,
                          const int* __restrict__ img_w_p,
                          float* __restrict__ out,
                          int total) {
    int i = blockIdx.x * blockDim.x + threadIdx.x;
    if (i >= total) return;
    int ow = i % OW;
    int t = i / OW;
    int oh = t % OH; t /= OH;
    int c = t % CTOT;
    int n = t / CTOT;
    float sx = (float)W0 / (float)img_w_p[0];
    float sy = (float)H0 / (float)img_h_p[0];
    float bx1 = boxes[n * 4 + 0] * sx;
    float by1 = boxes[n * 4 + 1] * sy;
    float bw = fmaxf(boxes[n * 4 + 2] * sx - bx1, 1.0f) / OW;
    float bh = fmaxf(boxes[n * 4 + 3] * sy - by1, 1.0f) / OH;
    int level = c >> 8;
    int cl = c & (CPL - 1);
    const float* f;
    int Hc, Wc; float inv_s;
    if (level == 0)      { f = f0 + (size_t)cl * P0; Hc = H0; Wc = W0; inv_s = 1.0f;  }
    else if (level == 1) { f = f1 + (size_t)cl * P1; Hc = H1; Wc = W1; inv_s = 0.5f;  }
    else                 { f = f2 + (size_t)cl * P2; Hc = H2; Wc = W2; inv_s = 0.25f; }
    float acc = 0.0f;
#pragma unroll
    for (int ry = 0; ry < 2; ++ry) {
        float Y = by1 + ((float)oh + 0.25f + 0.5f * ry) * bh;
        bool vy = (Y >= -1.0f) && (Y <= (float)H0);
        float Yc = fminf(fmaxf(Y, 0.0f), (float)(H0 - 1));
        int y0 = (int)Yc;
        float ly = Yc - (float)y0;
#pragma unroll
        for (int rx = 0; rx < 2; ++rx) {
            float X = bx1 + ((float)ow + 0.25f + 0.5f * rx) * bw;
            bool vx = (X >= -1.0f) && (X <= (float)W0);
            float Xc = fminf(fmaxf(X, 0.0f), (float)(W0 - 1));
            int x0 = (int)Xc;
            float lx = Xc - (float)x0;
            float v;
            if (level == 0) {
                int y1i = min(y0 + 1, H0 - 1), x1i = min(x0 + 1, W0 - 1);
                float hy = 1.0f - ly, hx = 1.0f - lx;
                float v00 = f[y0 * W0 + x0],  v01 = f[y0 * W0 + x1i];
                float v10 = f[y1i * W0 + x0], v11 = f[y1i * W0 + x1i];
                v = hy * (hx * v00 + lx * v01) + ly * (hx * v10 + lx * v11);
            } else {
                int yb, xb; float wy[3], wxl[3];
                axis_w3_fb(y0, H0, Hc, inv_s, ly, yb, wy);
                axis_w3_fb(x0, W0, Wc, inv_s, lx, xb, wxl);
                v = 0.0f;
#pragma unroll
                for (int a = 0; a < 3; ++a) {
                    int row = min(yb + a, Hc - 1) * Wc;
                    float s = 0.0f;
#pragma unroll
                    for (int b = 0; b < 3; ++b)
                        s += wxl[b] * f[row + min(xb + b, Wc - 1)];
                    v += wy[a] * s;
                }
            }
            if (vy && vx) acc += v;
        }
    }
    out[i] = acc * 0.25f;
}

// ---------------- launch ----------------------------------------------------
extern "C" void kernel_launch(void* const* d_in, const int* in_sizes, int n_in,
                              void* d_out, int out_size, void* d_ws, size_t ws_size,
                              hipStream_t stream) {
    const float* f0    = (const float*)d_in[0];
    const float* f1    = (const float*)d_in[1];
    const float* f2    = (const float*)d_in[2];
    const float* boxes = (const float*)d_in[3];
    const int* img_h_p = (const int*)d_in[4];
    const int* img_w_p = (const int*)d_in[5];
    float* out = (float*)d_out;
    int N = in_sizes[3] / 4;

    if (ws_size >= WS_BYTES) {
        unsigned short* ws = (unsigned short*)d_ws;
        unsigned short* T0 = ws + T0_OFF;
        unsigned short* T1 = ws + T1_OFF;
        unsigned short* T2 = ws + T2_OFF;
        int n0 = ((P0 + 63) / 64) * 4;   // 3800
        int n1 = ((P1 + 63) / 64) * 4;   // 952
        int n2 = ((P2 + 63) / 64) * 4;   // 240
        transpose_all_kernel<<<n0 + n1 + n2, 256, 0, stream>>>(
            f0, f1, f2, T0, T1, T2, n0, n0 + n1);
        roi_align_cl6_kernel<<<dim3(N, 6), 256, 0, stream>>>(
            T0, T1, T2, boxes, img_h_p, img_w_p, out);
    } else {
        int total = N * CTOT * OH * OW;
        roi_align_fused_fb_kernel<<<(total + 255) / 256, 256, 0, stream>>>(
            f0, f1, f2, boxes, img_h_p, img_w_p, out, total);
    }
}

// Round 6
// 158.287 us; speedup vs baseline: 1.0318x; 1.0093x over previous
//
#include <hip/hip_runtime.h>
#include <hip/hip_fp16.h>

#define H0 200
#define W0 304
#define H1 100
#define W1 152
#define H2 50
#define W2 76
#define CPL 256   // channels per level
#define CTOT 768
#define OH 7
#define OW 7
#define NPOS 49
#define CBLK 128   // channels per stage-2 block
#define SROWP 131  // sout row stride (floats): 128 + 3 pad (131%32=3, coprime)

#define P0 (H0*W0)   // 60800
#define P1 (H1*W1)   // 15200
#define P2 (H2*W2)   // 3800
#define T0_OFF ((size_t)0)
#define T1_OFF ((size_t)P0*CPL)
#define T2_OFF ((size_t)P0*CPL + (size_t)P1*CPL)
#define WS_ELEMS ((size_t)P0*CPL + (size_t)P1*CPL + (size_t)P2*CPL)
#define WS_BYTES (WS_ELEMS * 2)   // fp16 workspace: 40,857,600 B

__device__ __forceinline__ float hat01(float d) {
    return fmaxf(0.0f, 1.0f - fabsf(d));
}

__device__ __forceinline__ unsigned short f2h_rne(float x) {
    return __half_as_ushort(__float2half_rn(x));
}

// ------------- Stage 1: fused [C][P] fp32 -> [P][C] fp16 transpose ----------
__global__ void __launch_bounds__(256)
transpose_all_kernel(const float* __restrict__ f0, const float* __restrict__ f1,
                     const float* __restrict__ f2,
                     unsigned short* __restrict__ T0,
                     unsigned short* __restrict__ T1,
                     unsigned short* __restrict__ T2, int n0, int n01) {
    __shared__ unsigned short tile[64][72];   // [p_local][c_local]
    int b = blockIdx.x;
    const float* in; unsigned short* outp; int P; int rel;
    if (b < n0)       { in = f0; outp = T0; P = P0; rel = b; }
    else if (b < n01) { in = f1; outp = T1; P = P1; rel = b - n0; }
    else              { in = f2; outp = T2; P = P2; rel = b - n01; }
    int p0 = (rel >> 2) * 64;
    int c0 = (rel & 3) * 64;

    int q = threadIdx.x & 15;     // p-quad
    int r = threadIdx.x >> 4;     // 0..15 (c)
    bool full = (p0 + 64 <= P);
#pragma unroll
    for (int i = 0; i < 4; ++i) {
        int c = c0 + r + 16 * i;
        int p = p0 + 4 * q;
        float4 v;
        if (full) {
            v = *(const float4*)(in + (size_t)c * P + p);
        } else {
            v.x = (p + 0 < P) ? in[(size_t)c * P + p + 0] : 0.0f;
            v.y = (p + 1 < P) ? in[(size_t)c * P + p + 1] : 0.0f;
            v.z = (p + 2 < P) ? in[(size_t)c * P + p + 2] : 0.0f;
            v.w = (p + 3 < P) ? in[(size_t)c * P + p + 3] : 0.0f;
        }
        tile[4 * q + 0][r + 16 * i] = f2h_rne(v.x);
        tile[4 * q + 1][r + 16 * i] = f2h_rne(v.y);
        tile[4 * q + 2][r + 16 * i] = f2h_rne(v.z);
        tile[4 * q + 3][r + 16 * i] = f2h_rne(v.w);
    }
    __syncthreads();
    int q8 = threadIdx.x & 7;     // c-octet
    int r8 = threadIdx.x >> 3;    // 0..31 (p)
#pragma unroll
    for (int i = 0; i < 2; ++i) {
        int p = p0 + r8 + 32 * i;
        if (p < P) {
            uint4 w = *(const uint4*)&tile[r8 + 32 * i][8 * q8];
            *(uint4*)(outp + (size_t)p * CPL + c0 + 8 * q8) = w;
        }
    }
}

// ------------- Stage 2: channels-last RoIAlign, 128-ch slab per block -------
// Block = (n, j), j in [0,6): level = j>>1, channel half = j&1. Each block
// computes ALL 49 positions for its 128 channels -> contiguous output slab.
// R6: R2-R5 all plateaued at ~41us because the HIP compiler re-serializes
// gather loads (sinks them to uses, reuses dest regs -> vmcnt(0) per tap;
// VGPR=40-48 proves it). Escape hatch per guide: inline-asm
// global_load_dwordx4 (SADDR form: 32-bit voffset + uniform SGPR base) with
// explicit COUNTED s_waitcnt vmcnt(TX). Asm loads are opaque to
// SIInsertWaitcnts (no auto vmcnt(0)); "=&v" outputs force the double-buffer
// to stay live. Row pipeline per position: issue row r+1 -> vmcnt(TX) (row r
// ready, r+1 in flight) -> sched_barrier -> consume row r -> sched_barrier
// (WAR: consume must precede next issue into same parity).
template<int TY, int TX>
__device__ __forceinline__ void tap_loop(const unsigned short* __restrict__ T,
                                         const int (*__restrict__ s_idx)[6],
                                         const float (*__restrict__ s_w)[6],
                                         float (*__restrict__ sout)[SROWP],
                                         int pstart, int pcount, int col,
                                         unsigned laneByte) {
    const __half2 hz = __float2half2_rn(0.0f);
    for (int pi = 0; pi < pcount; ++pi) {
        const int pos = pstart + pi;
        const int oh = pos / 7;
        const int ow = pos - oh * 7;
        unsigned yo[TY]; float yw[TY];
#pragma unroll
        for (int j2 = 0; j2 < TY; ++j2) {
            yo[j2] = (unsigned)s_idx[oh][j2] + laneByte;
            yw[j2] = s_w[oh][j2];
        }
        unsigned xb[TX]; __half2 xw2[TX];
#pragma unroll
        for (int j2 = 0; j2 < TX; ++j2) {
            xb[j2] = (unsigned)s_idx[7 + ow][j2];
            xw2[j2] = __float2half2_rn(s_w[7 + ow][j2]);
        }

        uint4 buf[2][TX];   // static-indexed after unroll (parity r&1)
        // prologue: issue row 0 (asm -> cannot be sunk or collapsed)
#pragma unroll
        for (int b = 0; b < TX; ++b) {
            unsigned vo = yo[0] + xb[b];
            asm volatile("global_load_dwordx4 %0, %1, %2"
                         : "=&v"(buf[0][b]) : "v"(vo), "s"(T));
        }
        float a0 = 0.f, a1 = 0.f, a2 = 0.f, a3 = 0.f;
        float a4 = 0.f, a5 = 0.f, a6 = 0.f, a7 = 0.f;
#pragma unroll
        for (int r = 0; r < TY; ++r) {
            if (r + 1 < TY) {
                // issue next row into the other parity buffer
#pragma unroll
                for (int b = 0; b < TX; ++b) {
                    unsigned vo = yo[r + 1] + xb[b];
                    asm volatile("global_load_dwordx4 %0, %1, %2"
                                 : "=&v"(buf[(r + 1) & 1][b]) : "v"(vo), "s"(T));
                }
                asm volatile("s_waitcnt vmcnt(%0)" :: "n"(TX));
            } else {
                asm volatile("s_waitcnt vmcnt(0)");
            }
            __builtin_amdgcn_sched_barrier(0);   // consume must not hoist above wait
            __half2 q0 = hz, q1 = hz, q2 = hz, q3 = hz;
#pragma unroll
            for (int b = 0; b < TX; ++b) {
                const __half2 xw = xw2[b];
                const uint4 v = buf[r & 1][b];
                q0 = __hfma2(xw, *(const __half2*)&v.x, q0);
                q1 = __hfma2(xw, *(const __half2*)&v.y, q1);
                q2 = __hfma2(xw, *(const __half2*)&v.z, q2);
                q3 = __hfma2(xw, *(const __half2*)&v.w, q3);
            }
            const float wa = yw[r];
            a0 = fmaf(wa, __low2float(q0), a0);  a1 = fmaf(wa, __high2float(q0), a1);
            a2 = fmaf(wa, __low2float(q1), a2);  a3 = fmaf(wa, __high2float(q1), a3);
            a4 = fmaf(wa, __low2float(q2), a4);  a5 = fmaf(wa, __high2float(q2), a5);
            a6 = fmaf(wa, __low2float(q3), a6);  a7 = fmaf(wa, __high2float(q3), a7);
            __builtin_amdgcn_sched_barrier(0);   // WAR: pin consume before next issue
        }
        float4 o0, o1;
        o0.x = a0 * 0.25f; o0.y = a1 * 0.25f; o0.z = a2 * 0.25f; o0.w = a3 * 0.25f;
        o1.x = a4 * 0.25f; o1.y = a5 * 0.25f; o1.z = a6 * 0.25f; o1.w = a7 * 0.25f;
        *(float4*)(&sout[pos][col])     = o0;
        *(float4*)(&sout[pos][col + 4]) = o1;
    }
}

__global__ void __launch_bounds__(256, 5)
roi_align_cl6_kernel(const unsigned short* __restrict__ T0p,
                     const unsigned short* __restrict__ T1p,
                     const unsigned short* __restrict__ T2p,
                     const float* __restrict__ boxes,
                     const int* __restrict__ img_h_p,
                     const int* __restrict__ img_w_p,
                     float* __restrict__ out) {
    __shared__ float sout[NPOS][SROWP];    // [pos][c_local]
    __shared__ int   s_idx[14][6];         // BYTE offsets: [0..6]=y(oh), [7..13]=x(ow)
    __shared__ float s_w[14][6];

    const int n = blockIdx.x;
    const int j = blockIdx.y;              // 0..5
    const int lev = j >> 1;
    const int chalf = j & 1;
    const int tid = threadIdx.x;

    const unsigned short* T; int Hc, Wc; float inv_s;
    if (lev == 0)      { T = T0p; Hc = H0; Wc = W0; inv_s = 1.0f;  }
    else if (lev == 1) { T = T1p; Hc = H1; Wc = W1; inv_s = 0.5f;  }
    else               { T = T2p; Hc = H2; Wc = W2; inv_s = 0.25f; }

    if (tid < 14) {
        int axis = (tid >= 7) ? 1 : 0;     // 0 = y, 1 = x
        int o = tid - axis * 7;
        float sx = (float)W0 / (float)img_w_p[0];
        float sy = (float)H0 / (float)img_h_p[0];
        float a1v, bs; int Hf, Hca, mul;
        if (axis) {
            a1v = boxes[n * 4 + 0] * sx;
            float a2v = boxes[n * 4 + 2] * sx;
            bs = fmaxf(a2v - a1v, 1.0f) * (1.0f / (float)OW);
            Hf = W0; Hca = Wc; mul = 1;
        } else {
            a1v = boxes[n * 4 + 1] * sy;
            float a2v = boxes[n * 4 + 3] * sy;
            bs = fmaxf(a2v - a1v, 1.0f) * (1.0f / (float)OH);
            Hf = H0; Hca = Hc; mul = Wc;
        }
        int idx[6]; float w[6];
#pragma unroll
        for (int t = 0; t < 6; ++t) { idx[t] = 0; w[t] = 0.0f; }
        if (lev == 0) {
#pragma unroll
            for (int r2 = 0; r2 < 2; ++r2) {
                float Y = a1v + ((float)o + 0.25f + 0.5f * (float)r2) * bs;
                float v = (Y >= -1.0f && Y <= (float)Hf) ? 1.0f : 0.0f;
                float Yc = fminf(fmaxf(Y, 0.0f), (float)(Hf - 1));
                int y0 = (int)Yc; float lf = Yc - (float)y0;
                idx[2 * r2]     = y0;                  w[2 * r2]     = (1.0f - lf) * v;
                idx[2 * r2 + 1] = min(y0 + 1, Hf - 1); w[2 * r2 + 1] = lf * v;
            }
        } else {
            int bases[2]; float w3[2][3];
#pragma unroll
            for (int r2 = 0; r2 < 2; ++r2) {
                float Y = a1v + ((float)o + 0.25f + 0.5f * (float)r2) * bs;
                float v = (Y >= -1.0f && Y <= (float)Hf) ? 1.0f : 0.0f;
                float Yc = fminf(fmaxf(Y, 0.0f), (float)(Hf - 1));
                int y0 = (int)Yc; float lf = Yc - (float)y0; float hf = 1.0f - lf;
                int yf1 = min(y0 + 1, Hf - 1);
                float yc0 = fminf(fmaxf(((float)y0 + 0.5f) * inv_s - 0.5f, 0.0f), (float)(Hca - 1));
                float yc1 = fminf(fmaxf(((float)yf1 + 0.5f) * inv_s - 0.5f, 0.0f), (float)(Hca - 1));
                int b2 = (int)yc0;
                bases[r2] = b2;
#pragma unroll
                for (int t2 = 0; t2 < 3; ++t2) {
                    float j2 = (float)(b2 + t2);
                    w3[r2][t2] = v * (hf * hat01(yc0 - j2) + lf * hat01(yc1 - j2));
                }
            }
            int dmax = (lev == 1) ? 3 : 2;   // geometry: box<=272px -> gap<=2.43/1.21
            int d = min(max(bases[1] - bases[0], 0), dmax);
            w[0] += w3[0][0]; w[1] += w3[0][1]; w[2] += w3[0][2];
            w[d] += w3[1][0]; w[d + 1] += w3[1][1]; w[d + 2] += w3[1][2];
#pragma unroll
            for (int t = 0; t < 6; ++t) idx[t] = min(bases[0] + t, Hca - 1);
        }
        // pre-scale to BYTE offset in T (row stride Wc*CPL elems, 2B/elem)
#pragma unroll
        for (int t = 0; t < 6; ++t) { s_idx[tid][t] = idx[t] * mul * CPL * 2; s_w[tid][t] = w[t]; }
    }
    __syncthreads();

    const int grp = tid >> 4;              // 0..15: position group
    const int l16 = tid & 15;              // 0..15: 8 channels each
    const int col = l16 * 8;               // local channel within the 128-slab
    const unsigned laneByte = (unsigned)(chalf * CBLK + col) * 2u;

    // consecutive-position runs: group g owns positions [3g, 3g+3) (g=15: +4)
    const int pstart = 3 * grp;
    const int pcount = (grp == 15) ? 4 : 3;

    if (lev == 0)      tap_loop<4, 4>(T, s_idx, s_w, sout, pstart, pcount, col, laneByte);
    else if (lev == 1) tap_loop<6, 6>(T, s_idx, s_w, sout, pstart, pcount, col, laneByte);
    else               tap_loop<5, 5>(T, s_idx, s_w, sout, pstart, pcount, col, laneByte);
    __syncthreads();

    // Writeback: out[n][lev*256 + chalf*128 + c][p], contiguous 128*49 floats.
    size_t obase = (size_t)n * CTOT * NPOS + (size_t)(lev * CPL + chalf * CBLK) * NPOS;
    int c = tid / NPOS;
    int p = tid - c * NPOS;
    for (int i = tid; i < CBLK * NPOS; i += 256) {
        out[obase + i] = sout[p][c];
        c += 5; p += 11;                   // 256 = 5*49 + 11
        if (p >= NPOS) { p -= NPOS; ++c; }
    }
}

// ---------------- Fallback (R1 kernel) if ws too small ----------------------
__device__ __forceinline__ void axis_w3_fb(int yf0, int Hf, int Hc, float inv_s,
                                           float lf, int& base, float* w) {
    int yf1 = min(yf0 + 1, Hf - 1);
    float hf = 1.0f - lf;
    float yc0 = fminf(fmaxf(((float)yf0 + 0.5f) * inv_s - 0.5f, 0.0f), (float)(Hc - 1));
    float yc1 = fminf(fmaxf(((float)yf1 + 0.5f) * inv_s - 0.5f, 0.0f), (float)(Hc - 1));
    base = (int)yc0;
#pragma unroll
    for (int r = 0; r < 3; ++r) {
        float j = (float)(base + r);
        w[r] = hf * hat01(yc0 - j) + lf * hat01(yc1 - j);
    }
}

__global__ void __launch_bounds__(256)
roi_align_fused_fb_kernel(const float* __restrict__ f0,
                          const float* __restrict__ f1,
                          const float* __restrict__ f2,
                          const float* __restrict__ boxes,
                          const int* __restrict__ img_h_p,
                          const int* __restrict__ img_w_p,
                          float* __restrict__ out,
                          int total) {
    int i = blockIdx.x * blockDim.x + threadIdx.x;
    if (i >= total) return;
    int ow = i % OW;
    int t = i / OW;
    int oh = t % OH; t /= OH;
    int c = t % CTOT;
    int n = t / CTOT;
    float sx = (float)W0 / (float)img_w_p[0];
    float sy = (float)H0 / (float)img_h_p[0];
    float bx1 = boxes[n * 4 + 0] * sx;
    float by1 = boxes[n * 4 + 1] * sy;
    float bw = fmaxf(boxes[n * 4 + 2] * sx - bx1, 1.0f) / OW;
    float bh = fmaxf(boxes[n * 4 + 3] * sy - by1, 1.0f) / OH;
    int level = c >> 8;
    int cl = c & (CPL - 1);
    const float* f;
    int Hc, Wc; float inv_s;
    if (level == 0)      { f = f0 + (size_t)cl * P0; Hc = H0; Wc = W0; inv_s = 1.0f;  }
    else if (level == 1) { f = f1 + (size_t)cl * P1; Hc = H1; Wc = W1; inv_s = 0.5f;  }
    else                 { f = f2 + (size_t)cl * P2; Hc = H2; Wc = W2; inv_s = 0.25f; }
    float acc = 0.0f;
#pragma unroll
    for (int ry = 0; ry < 2; ++ry) {
        float Y = by1 + ((float)oh + 0.25f + 0.5f * ry) * bh;
        bool vy = (Y >= -1.0f) && (Y <= (float)H0);
        float Yc = fminf(fmaxf(Y, 0.0f), (float)(H0 - 1));
        int y0 = (int)Yc;
        float ly = Yc - (float)y0;
#pragma unroll
        for (int rx = 0; rx < 2; ++rx) {
            float X = bx1 + ((float)ow + 0.25f + 0.5f * rx) * bw;
            bool vx = (X >= -1.0f) && (X <= (float)W0);
            float Xc = fminf(fmaxf(X, 0.0f), (float)(W0 - 1));
            int x0 = (int)Xc;
            float lx = Xc - (float)x0;
            float v;
            if (level == 0) {
                int y1i = min(y0 + 1, H0 - 1), x1i = min(x0 + 1, W0 - 1);
                float hy = 1.0f - ly, hx = 1.0f - lx;
                float v00 = f[y0 * W0 + x0],  v01 = f[y0 * W0 + x1i];
                float v10 = f[y1i * W0 + x0], v11 = f[y1i * W0 + x1i];
                v = hy * (hx * v00 + lx * v01) + ly * (hx * v10 + lx * v11);
            } else {
                int yb, xb; float wy[3], wxl[3];
                axis_w3_fb(y0, H0, Hc, inv_s, ly, yb, wy);
                axis_w3_fb(x0, W0, Wc, inv_s, lx, xb, wxl);
                v = 0.0f;
#pragma unroll
                for (int a = 0; a < 3; ++a) {
                    int row = min(yb + a, Hc - 1) * Wc;
                    float s = 0.0f;
#pragma unroll
                    for (int b = 0; b < 3; ++b)
                        s += wxl[b] * f[row + min(xb + b, Wc - 1)];
                    v += wy[a] * s;
                }
            }
            if (vy && vx) acc += v;
        }
    }
    out[i] = acc * 0.25f;
}

// ---------------- launch ----------------------------------------------------
extern "C" void kernel_launch(void* const* d_in, const int* in_sizes, int n_in,
                              void* d_out, int out_size, void* d_ws, size_t ws_size,
                              hipStream_t stream) {
    const float* f0    = (const float*)d_in[0];
    const float* f1    = (const float*)d_in[1];
    const float* f2    = (const float*)d_in[2];
    const float* boxes = (const float*)d_in[3];
    const int* img_h_p = (const int*)d_in[4];
    const int* img_w_p = (const int*)d_in[5];
    float* out = (float*)d_out;
    int N = in_sizes[3] / 4;

    if (ws_size >= WS_BYTES) {
        unsigned short* ws = (unsigned short*)d_ws;
        unsigned short* T0 = ws + T0_OFF;
        unsigned short* T1 = ws + T1_OFF;
        unsigned short* T2 = ws + T2_OFF;
        int n0 = ((P0 + 63) / 64) * 4;   // 3800
        int n1 = ((P1 + 63) / 64) * 4;   // 952
        int n2 = ((P2 + 63) / 64) * 4;   // 240
        transpose_all_kernel<<<n0 + n1 + n2, 256, 0, stream>>>(
            f0, f1, f2, T0, T1, T2, n0, n0 + n1);
        roi_align_cl6_kernel<<<dim3(N, 6), 256, 0, stream>>>(
            T0, T1, T2, boxes, img_h_p, img_w_p, out);
    } else {
        int total = N * CTOT * OH * OW;
        roi_align_fused_fb_kernel<<<(total + 255) / 256, 256, 0, stream>>>(
            f0, f1, f2, boxes, img_h_p, img_w_p, out, total);
    }
}